// Round 2
// baseline (263.347 us; speedup 1.0000x reference)
//
#include <hip/hip_runtime.h>

// B=2, T=2048, D_MODEL=1024, H=16, Dh=64.  out = MHA_ALiBi(x) @ Wo^T
// cvt | fused QKV GEMM (256^2 8-phase schedule, V via LDS-transpose epilogue)
// | split-KV flash attn (static-margin exp2 softmax -> additive partials)
// | combine | O proj.
// R6 DIAGNOSTIC: qkv/flash/gemm_o each launched TWICE (idempotent) to measure
//   t_qkv + t_flash + t_gemm_o = dur_r2 - dur_r1 exactly. No functional change.

#define DEV __device__ __forceinline__

typedef __attribute__((ext_vector_type(8))) short short8;     // 8 bf16
typedef __attribute__((ext_vector_type(4))) float f32x4;      // MFMA C/D
typedef __attribute__((ext_vector_type(4))) unsigned short ushort4v;

DEV unsigned short f2bf(float f) {                            // RNE fp32->bf16
  unsigned u = __builtin_bit_cast(unsigned, f);
  u += 0x7fffu + ((u >> 16) & 1u);
  return (unsigned short)(u >> 16);
}
DEV float bf2f(unsigned short u) {
  unsigned x = ((unsigned)u) << 16;
  return __builtin_bit_cast(float, x);
}

DEV void gl2lds16(const void* g, void* l) {                   // 16B direct-to-LDS
  __builtin_amdgcn_global_load_lds(
      (const __attribute__((address_space(1))) void*)g,
      (__attribute__((address_space(3))) void*)l, 16, 0, 0);
}

// ---------------- fused fp32 -> bf16 convert (x + 4 weights) ---------------
__global__ __launch_bounds__(256) void cvt_all(
    const float* __restrict__ x, const float* __restrict__ wq,
    const float* __restrict__ wk, const float* __restrict__ wv,
    const float* __restrict__ wo, unsigned short* __restrict__ xb,
    unsigned short* __restrict__ wqb, unsigned short* __restrict__ wkb,
    unsigned short* __restrict__ wvb, unsigned short* __restrict__ wob) {
  int b = blockIdx.x;
  const float* s;
  unsigned short* d;
  int off;
  if (b < 4096)      { s = x;  d = xb;  off = b; }
  else if (b < 5120) { s = wq; d = wqb; off = b - 4096; }
  else if (b < 6144) { s = wk; d = wkb; off = b - 5120; }
  else if (b < 7168) { s = wv; d = wvb; off = b - 6144; }
  else               { s = wo; d = wob; off = b - 7168; }
  int i = (off * 256 + threadIdx.x) * 4;
  float4 v = *(const float4*)(s + i);
  ushort4v o = {f2bf(v.x), f2bf(v.y), f2bf(v.z), f2bf(v.w)};
  *(ushort4v*)(d + i) = o;
}

// ---------------- fused QKV GEMM: C[m,n] = sum_k A[m,k]*W[n,k] -------------
// 256x256 tile, BK=64, 8 waves (2x4), 8-phase counted-vmcnt schedule.
// grid (12,16): wsel = x>>2 (0:Q scale log2e/8 | 1:K | 2:V transpose-epilogue).
__global__ __launch_bounds__(512, 2) void gemm_qkv(
    const unsigned short* __restrict__ A, const unsigned short* __restrict__ Wq,
    const unsigned short* __restrict__ Wk, const unsigned short* __restrict__ Wv,
    unsigned short* __restrict__ Qo, unsigned short* __restrict__ Ko,
    unsigned short* __restrict__ Vo) {
  constexpr int K = 1024;
  __shared__ alignas(16) unsigned short Sm[65536];  // 128 KiB
  const int t = threadIdx.x;
  const int w = t >> 6, l = t & 63, l15 = l & 15, l4 = l >> 4;
  const int wr = w >> 2, wc = w & 3;
  const int wsel = blockIdx.x >> 2;
  const int n0 = (blockIdx.x & 3) * 256;
  const int m0 = blockIdx.y * 256;
  const unsigned short* Bmat = (wsel == 0) ? Wq : ((wsel == 1) ? Wk : Wv);

  const int srow = t >> 3;                    // 0..63 (row within 64-row call)
  const int sk = ((t & 7) ^ (srow & 7)) * 8;  // swizzled source k-unit (T2)

#define STG_A(T, H)                                                           \
  {                                                                           \
    gl2lds16(A + (m0 + (H)*128 + srow) * K + (T)*64 + sk,                     \
             &Sm[((T)&1) * 16384 + (H)*8192 + t * 8]);                        \
    gl2lds16(A + (m0 + (H)*128 + 64 + srow) * K + (T)*64 + sk,                \
             &Sm[((T)&1) * 16384 + (H)*8192 + 4096 + t * 8]);                 \
  }
#define STG_B(T, H)                                                           \
  {                                                                           \
    gl2lds16(Bmat + (n0 + (H)*128 + srow) * K + (T)*64 + sk,                  \
             &Sm[32768 + ((T)&1) * 16384 + (H)*8192 + t * 8]);                \
    gl2lds16(Bmat + (n0 + (H)*128 + 64 + srow) * K + (T)*64 + sk,             \
             &Sm[32768 + ((T)&1) * 16384 + (H)*8192 + 4096 + t * 8]);         \
  }

  f32x4 acc[8][4];
  {
    f32x4 z4 = {0.f, 0.f, 0.f, 0.f};
#pragma unroll
    for (int i = 0; i < 8; i++)
#pragma unroll
      for (int j = 0; j < 4; j++) acc[i][j] = z4;
  }
  short8 af[4][2], bf[2][2][2];

#define RD_AF(TT, QM)                                                         \
  {                                                                           \
    const unsigned short* Ab_ = &Sm[((TT)&1) * 16384];                        \
    _Pragma("unroll") for (int mi_ = 0; mi_ < 4; mi_++) {                     \
      _Pragma("unroll") for (int kk_ = 0; kk_ < 2; kk_++) {                   \
        af[mi_][kk_] = *(const short8*)&Ab_[                                  \
            (wr * 128 + (QM)*64 + mi_ * 16 + l15) * 64 +                      \
            (((kk_ * 4 + l4) ^ (l15 & 7)) * 8)];                              \
      }                                                                       \
    }                                                                         \
  }
#define RD_BF(TT, QN)                                                         \
  {                                                                           \
    const unsigned short* Bb_ = &Sm[32768 + ((TT)&1) * 16384];                \
    _Pragma("unroll") for (int ni_ = 0; ni_ < 2; ni_++) {                     \
      _Pragma("unroll") for (int kk_ = 0; kk_ < 2; kk_++) {                   \
        bf[(QN)][ni_][kk_] = *(const short8*)&Bb_[                            \
            (wc * 64 + (QN)*32 + ni_ * 16 + l15) * 64 +                       \
            (((kk_ * 4 + l4) ^ (l15 & 7)) * 8)];                              \
      }                                                                       \
    }                                                                         \
  }
#define DO_MFMA(QM, QN)                                                       \
  {                                                                           \
    _Pragma("unroll") for (int mi_ = 0; mi_ < 4; mi_++) {                     \
      _Pragma("unroll") for (int ni_ = 0; ni_ < 2; ni_++) {                   \
        _Pragma("unroll") for (int kk_ = 0; kk_ < 2; kk_++) {                 \
          acc[(QM)*4 + mi_][(QN)*2 + ni_] =                                   \
              __builtin_amdgcn_mfma_f32_16x16x32_bf16(                        \
                  af[mi_][kk_], bf[(QN)][ni_][kk_],                           \
                  acc[(QM)*4 + mi_][(QN)*2 + ni_], 0, 0, 0);                  \
        }                                                                     \
      }                                                                       \
    }                                                                         \
  }

#define VMW4 asm volatile("s_waitcnt vmcnt(4)" ::: "memory")
#define VMW0 asm volatile("s_waitcnt vmcnt(0)" ::: "memory")
#define NOW ((void)0)
#define PHASE(RDS, STG, MFMA_, WAIT)                                          \
  {                                                                           \
    RDS;                                                                      \
    STG;                                                                      \
    __builtin_amdgcn_sched_barrier(0);                                        \
    __builtin_amdgcn_s_barrier();                                             \
    __builtin_amdgcn_s_setprio(1);                                            \
    MFMA_;                                                                    \
    __builtin_amdgcn_s_setprio(0);                                            \
    __builtin_amdgcn_sched_barrier(0);                                        \
    WAIT;                                                                     \
    __builtin_amdgcn_s_barrier();                                             \
  }

  STG_B(0, 0); STG_B(0, 1); STG_A(0, 0); STG_A(0, 1);
  STG_B(1, 0); STG_B(1, 1);
  VMW4;
  __builtin_amdgcn_sched_barrier(0);
  __builtin_amdgcn_s_barrier();

#pragma unroll 1
  for (int i = 0; i < 7; ++i) {
    const int TA = 2 * i, TB = TA + 1;
    PHASE(RD_AF(TA, 0); RD_BF(TA, 0), STG_A(TB, 0),     DO_MFMA(0, 0), NOW);
    PHASE(RD_BF(TA, 1),               STG_A(TB, 1),     DO_MFMA(0, 1), NOW);
    PHASE(RD_AF(TA, 1),               STG_B(TA + 2, 0), DO_MFMA(1, 0), NOW);
    PHASE(NOW,                        STG_B(TA + 2, 1), DO_MFMA(1, 1), VMW4);
    PHASE(RD_AF(TB, 0); RD_BF(TB, 0), STG_A(TA + 2, 0), DO_MFMA(0, 0), NOW);
    PHASE(RD_BF(TB, 1),               STG_A(TA + 2, 1), DO_MFMA(0, 1), NOW);
    PHASE(RD_AF(TB, 1),               STG_B(TB + 2, 0), DO_MFMA(1, 0), NOW);
    PHASE(NOW,                        STG_B(TB + 2, 1), DO_MFMA(1, 1), VMW4);
  }
  PHASE(RD_AF(14, 0); RD_BF(14, 0), STG_A(15, 0), DO_MFMA(0, 0), NOW);
  PHASE(RD_BF(14, 1),               STG_A(15, 1), DO_MFMA(0, 1), NOW);
  PHASE(RD_AF(14, 1),               NOW,          DO_MFMA(1, 0), NOW);
  PHASE(NOW,                        NOW,          DO_MFMA(1, 1), VMW0);
  PHASE(RD_AF(15, 0); RD_BF(15, 0), NOW,          DO_MFMA(0, 0), NOW);
  PHASE(RD_BF(15, 1),               NOW,          DO_MFMA(0, 1), NOW);
  PHASE(RD_AF(15, 1),               NOW,          DO_MFMA(1, 0), NOW);
  PHASE(NOW,                        NOW,          DO_MFMA(1, 1), NOW);

#undef PHASE
#undef NOW
#undef VMW0
#undef VMW4
#undef DO_MFMA
#undef RD_BF
#undef RD_AF
#undef STG_B
#undef STG_A

  if (wsel != 2) {
    unsigned short* D = (wsel == 0) ? Qo : Ko;
    const float scale = (wsel == 0) ? 0.18033688011112042f : 1.0f;  // log2e/8
    const int zb = (n0 >> 6) + wc;
#pragma unroll
    for (int mi = 0; mi < 8; mi++)
#pragma unroll
      for (int r = 0; r < 4; r++) {
        int m = m0 + wr * 128 + mi * 16 + l4 * 4 + r;
        int b = m >> 11, tt = m & 2047;
        int z = b * 16 + zb;
#pragma unroll
        for (int ni = 0; ni < 4; ni++)
          D[(z * 2048 + tt) * 64 + ni * 16 + l15] = f2bf(acc[mi][ni][r] * scale);
      }
  } else {
    // V: per-wave LDS transpose [d 64][t 64] stride 72, two 64-t passes,
    // then coalesced 16B stores along t. Wave-private region -> no barrier.
    unsigned short* Tr = Sm + w * 4608;
    const int b = (m0 + wr * 128) >> 11, tbase = (m0 + wr * 128) & 2047;
    const int zg = b * 16 + (n0 >> 6) + wc;
#pragma unroll
    for (int p = 0; p < 2; p++) {
#pragma unroll
      for (int mi = 0; mi < 4; mi++)
#pragma unroll
        for (int ni = 0; ni < 4; ni++) {
          int mg = p * 4 + mi;
          ushort4v pk = {f2bf(acc[mg][ni][0]), f2bf(acc[mg][ni][1]),
                         f2bf(acc[mg][ni][2]), f2bf(acc[mg][ni][3])};
          *(ushort4v*)&Tr[(ni * 16 + l15) * 72 + mi * 16 + l4 * 4] = pk;
        }
      asm volatile("s_waitcnt lgkmcnt(0)" ::: "memory");
      __builtin_amdgcn_sched_barrier(0);
#pragma unroll
      for (int j = 0; j < 8; j++) {
        int idx = j * 64 + l;
        int d = idx >> 3, c = idx & 7;
        short8 v = *(const short8*)&Tr[d * 72 + c * 8];
        *(short8*)&Vo[(zg * 64 + d) * 2048 + tbase + p * 64 + c * 8] = v;
      }
      asm volatile("s_waitcnt lgkmcnt(0)" ::: "memory");  // reads before pass-2 writes
      __builtin_amdgcn_sched_barrier(0);
    }
  }
}

// ---------------- O projection: 128x64 tiles, grid (16,32) = 512 blocks ----
__global__ __launch_bounds__(256, 2) void gemm_o(
    const unsigned short* __restrict__ A, const unsigned short* __restrict__ Bm,
    float* __restrict__ C) {
  constexpr int K = 1024;
  __shared__ alignas(16) unsigned short Al[128 * 32];
  __shared__ alignas(16) unsigned short Bl[64 * 32];
  const int t = threadIdx.x;
  const int l = t & 63, l15 = l & 15, l4 = l >> 4;
  const int wm = ((t >> 6) & 1) * 64, wn = (t >> 7) * 32;
  const int m0 = blockIdx.y * 128, n0 = blockIdx.x * 64;

  f32x4 zero4 = {0.f, 0.f, 0.f, 0.f};
  f32x4 acc[4][2];
#pragma unroll
  for (int i = 0; i < 4; i++)
#pragma unroll
    for (int j = 0; j < 2; j++) acc[i][j] = zero4;

  const int row0 = t >> 2, seg = (t & 3) * 8;
  const unsigned short* Ag0 = A + (m0 + row0) * K + seg;
  const unsigned short* Ag1 = A + (m0 + row0 + 64) * K + seg;
  const unsigned short* Bg0 = Bm + (n0 + row0) * K + seg;

  for (int k0 = 0; k0 < K; k0 += 32) {
    gl2lds16(Ag0 + k0, &Al[t * 8]);
    gl2lds16(Ag1 + k0, &Al[2048 + t * 8]);
    gl2lds16(Bg0 + k0, &Bl[t * 8]);
    __syncthreads();
    short8 af[4], bf2[2];
#pragma unroll
    for (int mi = 0; mi < 4; mi++)
      af[mi] = *(const short8*)&Al[(wm + mi * 16 + l15) * 32 + l4 * 8];
#pragma unroll
    for (int ni = 0; ni < 2; ni++)
      bf2[ni] = *(const short8*)&Bl[(wn + ni * 16 + l15) * 32 + l4 * 8];
#pragma unroll
    for (int mi = 0; mi < 4; mi++)
#pragma unroll
      for (int ni = 0; ni < 2; ni++)
        acc[mi][ni] = __builtin_amdgcn_mfma_f32_16x16x32_bf16(
            af[mi], bf2[ni], acc[mi][ni], 0, 0, 0);
    __syncthreads();
  }
#pragma unroll
  for (int mi = 0; mi < 4; mi++)
#pragma unroll
    for (int r = 0; r < 4; r++) {
      int m = m0 + wm + mi * 16 + l4 * 4 + r;
      float* cp = C + m * 1024 + n0 + wn + l15;
      cp[0] = acc[mi][0][r];
      cp[16] = acc[mi][1][r];
    }
}

// ---------------- Split-KV flash attention ---------------------------------
__global__ __launch_bounds__(256, 3) void flash_alibi(
    const unsigned short* __restrict__ Q, const unsigned short* __restrict__ Kb,
    const unsigned short* __restrict__ Vt, unsigned short* __restrict__ O0,
    unsigned short* __restrict__ O1, float* __restrict__ L0,
    float* __restrict__ L1) {
  __shared__ alignas(16) unsigned short Kl[2 * 4096];
  __shared__ alignas(16) unsigned short Vl[2 * 4096];
  __shared__ alignas(16) unsigned short Pl[4 * 2304];  // 4 waves x 32 x 72
  const int t = threadIdx.x, w = t >> 6, l = t & 63, l15 = l & 15, l4 = l >> 4;
  const int g = blockIdx.x;
  const int qt = 15 - (g >> 6);
  const int z = (g & 63) >> 1, s = g & 1;
  const int q0 = qt * 128, h = z & 15;
  const float slope2 = exp2f(-0.5f * (float)(h + 1)) * 1.4426950408889634f;
  const int qrow = q0 + w * 32;

  short8 aq[2][2];
#pragma unroll
  for (int mi = 0; mi < 2; mi++)
#pragma unroll
    for (int ks = 0; ks < 2; ks++)
      aq[mi][ks] = *(const short8*)&Q[(z * 2048 + qrow + mi * 16 + l15) * 64 +
                                      ks * 32 + l4 * 8];

  f32x4 binit[2];
#pragma unroll
  for (int mi = 0; mi < 2; mi++)
#pragma unroll
    for (int r = 0; r < 4; r++)
      binit[mi][r] = -(slope2 * (float)(qrow + mi * 16 + l4 * 4 + r) + 10.0f);

  f32x4 zero4 = {0.f, 0.f, 0.f, 0.f};
  f32x4 o[2][4];
  float lsum[2][4];
#pragma unroll
  for (int mi = 0; mi < 2; mi++)
#pragma unroll
    for (int j = 0; j < 4; j++) {
      o[mi][j] = zero4;
      lsum[mi][j] = 0.f;
    }

  const int row0 = t >> 2, seg8 = (t & 3) * 8;
  const int it0 = s ? (qt + 1) : 0;
  const int nt = qt + 1;

#define ISSUE_LOADS(KV0, BUF)                                                \
  {                                                                          \
    unsigned short* Kd = &Kl[(BUF) * 4096];                                  \
    unsigned short* Vd = &Vl[(BUF) * 4096];                                  \
    gl2lds16(&Kb[(z * 2048 + (KV0) + row0) * 64 + seg8], &Kd[t * 8]);        \
    gl2lds16(&Kb[(z * 2048 + (KV0) + row0) * 64 + 32 + seg8],                \
             &Kd[2048 + t * 8]);                                             \
    gl2lds16(&Vt[(z * 64 + row0) * 2048 + (KV0) + seg8], &Vd[t * 8]);        \
    gl2lds16(&Vt[(z * 64 + row0) * 2048 + (KV0) + 32 + seg8],                \
             &Vd[2048 + t * 8]);                                             \
  }

  ISSUE_LOADS(it0 * 64, 0)

  for (int ii = 0; ii < nt; ++ii) {
    __syncthreads();  // buf (ii&1) ready
    const int kv0 = (it0 + ii) * 64;
    if (ii + 1 < nt) ISSUE_LOADS(kv0 + 64, (ii + 1) & 1)
    if (kv0 > qrow + 31) continue;  // fully masked for this wave
    const unsigned short* Kc = &Kl[(ii & 1) * 4096];
    const unsigned short* Vc = &Vl[(ii & 1) * 4096];

    f32x4 sc[2][4];
#pragma unroll
    for (int mi = 0; mi < 2; mi++)
#pragma unroll
      for (int ni = 0; ni < 4; ni++) sc[mi][ni] = binit[mi];
#pragma unroll
    for (int ks = 0; ks < 2; ks++) {
      short8 bk[4];
#pragma unroll
      for (int ni = 0; ni < 4; ni++)
        bk[ni] = *(const short8*)&Kc[(ks * 64 + ni * 16 + l15) * 32 + l4 * 8];
#pragma unroll
      for (int mi = 0; mi < 2; mi++)
#pragma unroll
        for (int ni = 0; ni < 4; ni++)
          sc[mi][ni] = __builtin_amdgcn_mfma_f32_16x16x32_bf16(
              aq[mi][ks], bk[ni], sc[mi][ni], 0, 0, 0);
    }

    const bool needMask = (kv0 + 63 > qrow);  // diagonal tile (either side)
    float jf[4];
#pragma unroll
    for (int ni = 0; ni < 4; ni++) jf[ni] = (float)(kv0 + ni * 16 + l15);

#pragma unroll
    for (int mi = 0; mi < 2; mi++)
#pragma unroll
      for (int r = 0; r < 4; r++) {
        float ps[4];
#pragma unroll
        for (int ni = 0; ni < 4; ni++)
          ps[ni] = __builtin_amdgcn_exp2f(fmaf(slope2, jf[ni], sc[mi][ni][r]));
        if (needMask) {
          int qi = qrow + mi * 16 + l4 * 4 + r;
#pragma unroll
          for (int ni = 0; ni < 4; ni++)
            if (kv0 + ni * 16 + l15 > qi) ps[ni] = 0.f;
        }
        lsum[mi][r] += (ps[0] + ps[1]) + (ps[2] + ps[3]);
        int row = mi * 16 + l4 * 4 + r;
        unsigned short* pp = &Pl[w * 2304 + row * 72 + (l15 & 7)];
#pragma unroll
        for (int ni = 0; ni < 4; ni++)
          pp[((ni * 2 + (l15 >> 3)) ^ l4) * 8] = f2bf(ps[ni]);
      }

    asm volatile("s_waitcnt lgkmcnt(0)" ::: "memory");  // wave-private P region

    const int rsw = (l15 >> 2) & 3;
#pragma unroll
    for (int ks = 0; ks < 2; ks++) {
      short8 pf[2], vf[4];
#pragma unroll
      for (int mi = 0; mi < 2; mi++)
        pf[mi] = *(const short8*)&Pl[w * 2304 + (mi * 16 + l15) * 72 +
                                     ((ks * 4 + l4) ^ rsw) * 8];
#pragma unroll
      for (int nd = 0; nd < 4; nd++)
        vf[nd] = *(const short8*)&Vc[(ks * 64 + nd * 16 + l15) * 32 + l4 * 8];
#pragma unroll
      for (int mi = 0; mi < 2; mi++)
#pragma unroll
        for (int nd = 0; nd < 4; nd++)
          o[mi][nd] = __builtin_amdgcn_mfma_f32_16x16x32_bf16(
              pf[mi], vf[nd], o[mi][nd], 0, 0, 0);
    }
  }
#undef ISSUE_LOADS

  // epilogue: write PARTIAL O (no normalization) + partial l
  unsigned short* Op = s ? O1 : O0;
  float* Lp = s ? L1 : L0;
#pragma unroll
  for (int mi = 0; mi < 2; mi++)
#pragma unroll
    for (int r = 0; r < 4; r++) {
      float lv = lsum[mi][r];
#pragma unroll
      for (int off = 1; off < 16; off <<= 1) lv += __shfl_xor(lv, off);
      int tg = qrow + mi * 16 + l4 * 4 + r;
      if (l15 == 0) Lp[z * 2048 + tg] = lv;
      unsigned short* op = &Op[(z * 2048 + tg) * 64 + l15];
#pragma unroll
      for (int nd = 0; nd < 4; nd++) op[nd * 16] = f2bf(o[mi][nd][r]);
    }
}

// ---------------- combine: O=(O0+O1)/(l0+l1), (z,t,d) -> (b,t,h*64+d) ------
__global__ __launch_bounds__(256) void combine(
    const unsigned short* __restrict__ O0, const unsigned short* __restrict__ O1,
    const float* __restrict__ L0, const float* __restrict__ L1,
    unsigned short* __restrict__ Ob) {
  int idx = (blockIdx.x * 256 + threadIdx.x) * 8;  // flat (z,t,d)
  int z = idx >> 17, rem = idx & 131071;
  int tt = rem >> 6, d = rem & 63;
  short8 a = *(const short8*)(O0 + idx);
  short8 b = *(const short8*)(O1 + idx);
  float inv = 1.0f / (L0[z * 2048 + tt] + L1[z * 2048 + tt]);
  short8 o;
#pragma unroll
  for (int j = 0; j < 8; j++) {
    float v = (bf2f((unsigned short)a[j]) + bf2f((unsigned short)b[j])) * inv;
    o[j] = (short)f2bf(v);
  }
  int bq = z >> 4, h = z & 15;
  *(short8*)(Ob + (bq * 2048 + tt) * 1024 + h * 64 + d) = o;
}

// ---------------------------------------------------------------------------
extern "C" void kernel_launch(void* const* d_in, const int* in_sizes, int n_in,
                              void* d_out, int out_size, void* d_ws,
                              size_t ws_size, hipStream_t stream) {
  const float* x = (const float*)d_in[0];
  const float* Wq = (const float*)d_in[1];
  const float* Wk = (const float*)d_in[2];
  const float* Wv = (const float*)d_in[3];
  const float* Wo = (const float*)d_in[4];

  char* p = (char*)d_ws;
  unsigned short* xb = (unsigned short*)p;  p += 4096 * 1024 * 2;  // O0 after qkv
  unsigned short* wqb = (unsigned short*)p; p += 1024 * 1024 * 2;
  unsigned short* wkb = (unsigned short*)p; p += 1024 * 1024 * 2;
  unsigned short* wvb = (unsigned short*)p; p += 1024 * 1024 * 2;
  unsigned short* wob = (unsigned short*)p; p += 1024 * 1024 * 2;
  unsigned short* Qb = (unsigned short*)p;  p += 32 * 2048 * 64 * 2;  // Ob after flash
  unsigned short* Kbf = (unsigned short*)p; p += 32 * 2048 * 64 * 2;
  unsigned short* Vtb = (unsigned short*)p; p += 32 * 2048 * 64 * 2;
  unsigned short* O1 = (unsigned short*)p;  p += 32 * 2048 * 64 * 2;
  float* L0 = (float*)p;                    p += 32 * 2048 * 4;
  float* L1 = (float*)p;                    p += 32 * 2048 * 4;
  unsigned short* O0 = xb;  // xb dead after gemm_qkv
  unsigned short* Ob = Qb;  // Qb dead after flash

  cvt_all<<<8192, 256, 0, stream>>>(x, Wq, Wk, Wv, Wo, xb, wqb, wkb, wvb, wob);
  // DIAG x2: duplicated launches (idempotent). qkv2 runs BEFORE flash so xb is
  // still intact; flash2 re-reads intact Qb/Kbf/Vtb and rewrites same partials.
  gemm_qkv<<<dim3(12, 16), 512, 0, stream>>>(xb, wqb, wkb, wvb, Qb, Kbf, Vtb);
  gemm_qkv<<<dim3(12, 16), 512, 0, stream>>>(xb, wqb, wkb, wvb, Qb, Kbf, Vtb);
  flash_alibi<<<1024, 256, 0, stream>>>(Qb, Kbf, Vtb, O0, O1, L0, L1);
  flash_alibi<<<1024, 256, 0, stream>>>(Qb, Kbf, Vtb, O0, O1, L0, L1);
  combine<<<2048, 256, 0, stream>>>(O0, O1, L0, L1, Ob);
  gemm_o<<<dim3(16, 32), 256, 0, stream>>>(Ob, wob, (float*)d_out);
  gemm_o<<<dim3(16, 32), 256, 0, stream>>>(Ob, wob, (float*)d_out);
}

// Round 3
// 164.845 us; speedup vs baseline: 1.5975x; 1.5975x over previous
//
#include <hip/hip_runtime.h>

// B=2, T=2048, D_MODEL=1024, H=16, Dh=64.  out = MHA_ALiBi(x) @ Wo^T
// cvt | fused QKV GEMM (256^2 8-phase; V epilogue writes bit2<->3 t-permuted
// Vt) | flash attn v2 (swapped QK^T 32x32, in-register P via permuted-kappa
// PV, XOR-swizzled K/V LDS) | combine | O proj (XCD-swizzled).
// R7: flash v2 + gemm_o XCD swizzle.

#define DEV __device__ __forceinline__

typedef __attribute__((ext_vector_type(8))) short short8;     // 8 bf16
typedef __attribute__((ext_vector_type(4))) float f32x4;      // MFMA C/D 16x16
typedef __attribute__((ext_vector_type(16))) float f32x16;    // MFMA C/D 32x32
typedef __attribute__((ext_vector_type(4))) unsigned short ushort4v;
typedef __attribute__((ext_vector_type(4))) unsigned uint4v;

DEV unsigned short f2bf(float f) {                            // RNE fp32->bf16
  unsigned u = __builtin_bit_cast(unsigned, f);
  u += 0x7fffu + ((u >> 16) & 1u);
  return (unsigned short)(u >> 16);
}
DEV float bf2f(unsigned short u) {
  unsigned x = ((unsigned)u) << 16;
  return __builtin_bit_cast(float, x);
}
DEV unsigned cvtpk_bf(float lo, float hi) {                   // 2xf32 -> 2xbf16
  unsigned r;
  asm("v_cvt_pk_bf16_f32 %0, %1, %2" : "=v"(r) : "v"(lo), "v"(hi));
  return r;
}

DEV void gl2lds16(const void* g, void* l) {                   // 16B direct-to-LDS
  __builtin_amdgcn_global_load_lds(
      (const __attribute__((address_space(1))) void*)g,
      (__attribute__((address_space(3))) void*)l, 16, 0, 0);
}

// ---------------- fused fp32 -> bf16 convert (x + 4 weights) ---------------
__global__ __launch_bounds__(256) void cvt_all(
    const float* __restrict__ x, const float* __restrict__ wq,
    const float* __restrict__ wk, const float* __restrict__ wv,
    const float* __restrict__ wo, unsigned short* __restrict__ xb,
    unsigned short* __restrict__ wqb, unsigned short* __restrict__ wkb,
    unsigned short* __restrict__ wvb, unsigned short* __restrict__ wob) {
  int b = blockIdx.x;
  const float* s;
  unsigned short* d;
  int off;
  if (b < 4096)      { s = x;  d = xb;  off = b; }
  else if (b < 5120) { s = wq; d = wqb; off = b - 4096; }
  else if (b < 6144) { s = wk; d = wkb; off = b - 5120; }
  else if (b < 7168) { s = wv; d = wvb; off = b - 6144; }
  else               { s = wo; d = wob; off = b - 7168; }
  int i = (off * 256 + threadIdx.x) * 4;
  float4 v = *(const float4*)(s + i);
  ushort4v o = {f2bf(v.x), f2bf(v.y), f2bf(v.z), f2bf(v.w)};
  *(ushort4v*)(d + i) = o;
}

// ---------------- fused QKV GEMM: C[m,n] = sum_k A[m,k]*W[n,k] -------------
// 256x256 tile, BK=64, 8 waves (2x4), 8-phase counted-vmcnt schedule.
// grid (12,16): wsel = x>>2 (0:Q scale log2e/8 | 1:K | 2:V transpose-epilogue).
// V epilogue writes Vt in t-bit2<->bit3-permuted order (consumed by flash v2).
__global__ __launch_bounds__(512, 2) void gemm_qkv(
    const unsigned short* __restrict__ A, const unsigned short* __restrict__ Wq,
    const unsigned short* __restrict__ Wk, const unsigned short* __restrict__ Wv,
    unsigned short* __restrict__ Qo, unsigned short* __restrict__ Ko,
    unsigned short* __restrict__ Vo) {
  constexpr int K = 1024;
  __shared__ alignas(16) unsigned short Sm[65536];  // 128 KiB
  const int t = threadIdx.x;
  const int w = t >> 6, l = t & 63, l15 = l & 15, l4 = l >> 4;
  const int wr = w >> 2, wc = w & 3;
  const int wsel = blockIdx.x >> 2;
  const int n0 = (blockIdx.x & 3) * 256;
  const int m0 = blockIdx.y * 256;
  const unsigned short* Bmat = (wsel == 0) ? Wq : ((wsel == 1) ? Wk : Wv);

  const int srow = t >> 3;                    // 0..63 (row within 64-row call)
  const int sk = ((t & 7) ^ (srow & 7)) * 8;  // swizzled source k-unit (T2)

#define STG_A(T, H)                                                           \
  {                                                                           \
    gl2lds16(A + (m0 + (H)*128 + srow) * K + (T)*64 + sk,                     \
             &Sm[((T)&1) * 16384 + (H)*8192 + t * 8]);                        \
    gl2lds16(A + (m0 + (H)*128 + 64 + srow) * K + (T)*64 + sk,                \
             &Sm[((T)&1) * 16384 + (H)*8192 + 4096 + t * 8]);                 \
  }
#define STG_B(T, H)                                                           \
  {                                                                           \
    gl2lds16(Bmat + (n0 + (H)*128 + srow) * K + (T)*64 + sk,                  \
             &Sm[32768 + ((T)&1) * 16384 + (H)*8192 + t * 8]);                \
    gl2lds16(Bmat + (n0 + (H)*128 + 64 + srow) * K + (T)*64 + sk,             \
             &Sm[32768 + ((T)&1) * 16384 + (H)*8192 + 4096 + t * 8]);         \
  }

  f32x4 acc[8][4];
  {
    f32x4 z4 = {0.f, 0.f, 0.f, 0.f};
#pragma unroll
    for (int i = 0; i < 8; i++)
#pragma unroll
      for (int j = 0; j < 4; j++) acc[i][j] = z4;
  }
  short8 af[4][2], bf[2][2][2];

#define RD_AF(TT, QM)                                                         \
  {                                                                           \
    const unsigned short* Ab_ = &Sm[((TT)&1) * 16384];                        \
    _Pragma("unroll") for (int mi_ = 0; mi_ < 4; mi_++) {                     \
      _Pragma("unroll") for (int kk_ = 0; kk_ < 2; kk_++) {                   \
        af[mi_][kk_] = *(const short8*)&Ab_[                                  \
            (wr * 128 + (QM)*64 + mi_ * 16 + l15) * 64 +                      \
            (((kk_ * 4 + l4) ^ (l15 & 7)) * 8)];                              \
      }                                                                       \
    }                                                                         \
  }
#define RD_BF(TT, QN)                                                         \
  {                                                                           \
    const unsigned short* Bb_ = &Sm[32768 + ((TT)&1) * 16384];                \
    _Pragma("unroll") for (int ni_ = 0; ni_ < 2; ni_++) {                     \
      _Pragma("unroll") for (int kk_ = 0; kk_ < 2; kk_++) {                   \
        bf[(QN)][ni_][kk_] = *(const short8*)&Bb_[                            \
            (wc * 64 + (QN)*32 + ni_ * 16 + l15) * 64 +                       \
            (((kk_ * 4 + l4) ^ (l15 & 7)) * 8)];                              \
      }                                                                       \
    }                                                                         \
  }
#define DO_MFMA(QM, QN)                                                       \
  {                                                                           \
    _Pragma("unroll") for (int mi_ = 0; mi_ < 4; mi_++) {                     \
      _Pragma("unroll") for (int ni_ = 0; ni_ < 2; ni_++) {                   \
        _Pragma("unroll") for (int kk_ = 0; kk_ < 2; kk_++) {                 \
          acc[(QM)*4 + mi_][(QN)*2 + ni_] =                                   \
              __builtin_amdgcn_mfma_f32_16x16x32_bf16(                        \
                  af[mi_][kk_], bf[(QN)][ni_][kk_],                           \
                  acc[(QM)*4 + mi_][(QN)*2 + ni_], 0, 0, 0);                  \
        }                                                                     \
      }                                                                       \
    }                                                                         \
  }

#define VMW4 asm volatile("s_waitcnt vmcnt(4)" ::: "memory")
#define VMW0 asm volatile("s_waitcnt vmcnt(0)" ::: "memory")
#define NOW ((void)0)
#define PHASE(RDS, STG, MFMA_, WAIT)                                          \
  {                                                                           \
    RDS;                                                                      \
    STG;                                                                      \
    __builtin_amdgcn_sched_barrier(0);                                        \
    __builtin_amdgcn_s_barrier();                                             \
    __builtin_amdgcn_s_setprio(1);                                            \
    MFMA_;                                                                    \
    __builtin_amdgcn_s_setprio(0);                                            \
    __builtin_amdgcn_sched_barrier(0);                                        \
    WAIT;                                                                     \
    __builtin_amdgcn_s_barrier();                                             \
  }

  STG_B(0, 0); STG_B(0, 1); STG_A(0, 0); STG_A(0, 1);
  STG_B(1, 0); STG_B(1, 1);
  VMW4;
  __builtin_amdgcn_sched_barrier(0);
  __builtin_amdgcn_s_barrier();

#pragma unroll 1
  for (int i = 0; i < 7; ++i) {
    const int TA = 2 * i, TB = TA + 1;
    PHASE(RD_AF(TA, 0); RD_BF(TA, 0), STG_A(TB, 0),     DO_MFMA(0, 0), NOW);
    PHASE(RD_BF(TA, 1),               STG_A(TB, 1),     DO_MFMA(0, 1), NOW);
    PHASE(RD_AF(TA, 1),               STG_B(TA + 2, 0), DO_MFMA(1, 0), NOW);
    PHASE(NOW,                        STG_B(TA + 2, 1), DO_MFMA(1, 1), VMW4);
    PHASE(RD_AF(TB, 0); RD_BF(TB, 0), STG_A(TA + 2, 0), DO_MFMA(0, 0), NOW);
    PHASE(RD_BF(TB, 1),               STG_A(TA + 2, 1), DO_MFMA(0, 1), NOW);
    PHASE(RD_AF(TB, 1),               STG_B(TB + 2, 0), DO_MFMA(1, 0), NOW);
    PHASE(NOW,                        STG_B(TB + 2, 1), DO_MFMA(1, 1), VMW4);
  }
  PHASE(RD_AF(14, 0); RD_BF(14, 0), STG_A(15, 0), DO_MFMA(0, 0), NOW);
  PHASE(RD_BF(14, 1),               STG_A(15, 1), DO_MFMA(0, 1), NOW);
  PHASE(RD_AF(14, 1),               NOW,          DO_MFMA(1, 0), NOW);
  PHASE(NOW,                        NOW,          DO_MFMA(1, 1), VMW0);
  PHASE(RD_AF(15, 0); RD_BF(15, 0), NOW,          DO_MFMA(0, 0), NOW);
  PHASE(RD_BF(15, 1),               NOW,          DO_MFMA(0, 1), NOW);
  PHASE(RD_AF(15, 1),               NOW,          DO_MFMA(1, 0), NOW);
  PHASE(NOW,                        NOW,          DO_MFMA(1, 1), NOW);

#undef PHASE
#undef NOW
#undef VMW0
#undef VMW4
#undef DO_MFMA
#undef RD_BF
#undef RD_AF
#undef STG_B
#undef STG_A

  if (wsel != 2) {
    unsigned short* D = (wsel == 0) ? Qo : Ko;
    const float scale = (wsel == 0) ? 0.18033688011112042f : 1.0f;  // log2e/8
    const int zb = (n0 >> 6) + wc;
#pragma unroll
    for (int mi = 0; mi < 8; mi++)
#pragma unroll
      for (int r = 0; r < 4; r++) {
        int m = m0 + wr * 128 + mi * 16 + l4 * 4 + r;
        int b = m >> 11, tt = m & 2047;
        int z = b * 16 + zb;
#pragma unroll
        for (int ni = 0; ni < 4; ni++)
          D[(z * 2048 + tt) * 64 + ni * 16 + l15] = f2bf(acc[mi][ni][r] * scale);
      }
  } else {
    // V: per-wave LDS transpose [d 64][t 64] stride 72, two 64-t passes, then
    // coalesced 16B stores along t in BIT2<->BIT3-PERMUTED t order:
    // Vt_perm[.. + 8c + i] = V[t = 16*(c>>1) + 4*(c&1) + (i&3) + 8*(i>>2)].
    unsigned short* Tr = Sm + w * 4608;
    const int b = (m0 + wr * 128) >> 11, tbase = (m0 + wr * 128) & 2047;
    const int zg = b * 16 + (n0 >> 6) + wc;
#pragma unroll
    for (int p = 0; p < 2; p++) {
#pragma unroll
      for (int mi = 0; mi < 4; mi++)
#pragma unroll
        for (int ni = 0; ni < 4; ni++) {
          int mg = p * 4 + mi;
          ushort4v pk = {f2bf(acc[mg][ni][0]), f2bf(acc[mg][ni][1]),
                         f2bf(acc[mg][ni][2]), f2bf(acc[mg][ni][3])};
          *(ushort4v*)&Tr[(ni * 16 + l15) * 72 + mi * 16 + l4 * 4] = pk;
        }
      asm volatile("s_waitcnt lgkmcnt(0)" ::: "memory");
      __builtin_amdgcn_sched_barrier(0);
#pragma unroll
      for (int j = 0; j < 8; j++) {
        int idx = j * 64 + l;
        int d = idx >> 3, c = idx & 7;
        int t0 = (c >> 1) * 16 + (c & 1) * 4;
        ushort4v lo4 = *(const ushort4v*)&Tr[d * 72 + t0];
        ushort4v hi4 = *(const ushort4v*)&Tr[d * 72 + t0 + 8];
        short8 v = {(short)lo4[0], (short)lo4[1], (short)lo4[2], (short)lo4[3],
                    (short)hi4[0], (short)hi4[1], (short)hi4[2], (short)hi4[3]};
        *(short8*)&Vo[(zg * 64 + d) * 2048 + tbase + p * 64 + c * 8] = v;
      }
      asm volatile("s_waitcnt lgkmcnt(0)" ::: "memory");  // reads before pass-2
      __builtin_amdgcn_sched_barrier(0);
    }
  }
}

// ---------------- O projection: 128x64 tiles, flat grid 512, XCD-swizzled --
__global__ __launch_bounds__(256, 2) void gemm_o(
    const unsigned short* __restrict__ A, const unsigned short* __restrict__ Bm,
    float* __restrict__ C) {
  constexpr int K = 1024;
  __shared__ alignas(16) unsigned short Al[128 * 32];
  __shared__ alignas(16) unsigned short Bl[64 * 32];
  const int t = threadIdx.x;
  const int l = t & 63, l15 = l & 15, l4 = l >> 4;
  const int wm = ((t >> 6) & 1) * 64, wn = (t >> 7) * 32;
  // XCD-bijective swizzle: each XCD gets 4 contiguous m-panels x all 16 n.
  const int sblk = (blockIdx.x & 7) * 64 + (blockIdx.x >> 3);
  const int m0 = (sblk >> 4) * 128, n0 = (sblk & 15) * 64;

  f32x4 zero4 = {0.f, 0.f, 0.f, 0.f};
  f32x4 acc[4][2];
#pragma unroll
  for (int i = 0; i < 4; i++)
#pragma unroll
    for (int j = 0; j < 2; j++) acc[i][j] = zero4;

  const int row0 = t >> 2, seg = (t & 3) * 8;
  const unsigned short* Ag0 = A + (m0 + row0) * K + seg;
  const unsigned short* Ag1 = A + (m0 + row0 + 64) * K + seg;
  const unsigned short* Bg0 = Bm + (n0 + row0) * K + seg;

  for (int k0 = 0; k0 < K; k0 += 32) {
    gl2lds16(Ag0 + k0, &Al[t * 8]);
    gl2lds16(Ag1 + k0, &Al[2048 + t * 8]);
    gl2lds16(Bg0 + k0, &Bl[t * 8]);
    __syncthreads();
    short8 af[4], bf2[2];
#pragma unroll
    for (int mi = 0; mi < 4; mi++)
      af[mi] = *(const short8*)&Al[(wm + mi * 16 + l15) * 32 + l4 * 8];
#pragma unroll
    for (int ni = 0; ni < 2; ni++)
      bf2[ni] = *(const short8*)&Bl[(wn + ni * 16 + l15) * 32 + l4 * 8];
#pragma unroll
    for (int mi = 0; mi < 4; mi++)
#pragma unroll
      for (int ni = 0; ni < 2; ni++)
        acc[mi][ni] = __builtin_amdgcn_mfma_f32_16x16x32_bf16(
            af[mi], bf2[ni], acc[mi][ni], 0, 0, 0);
    __syncthreads();
  }
#pragma unroll
  for (int mi = 0; mi < 4; mi++)
#pragma unroll
    for (int r = 0; r < 4; r++) {
      int m = m0 + wm + mi * 16 + l4 * 4 + r;
      float* cp = C + m * 1024 + n0 + wn + l15;
      cp[0] = acc[mi][0][r];
      cp[16] = acc[mi][1][r];
    }
}

// ---------------- Split-KV flash attention v2 ------------------------------
// grid 1024: qt = 15-(g>>6) (heavy first); z = (g&63)>>1; s = g&1.
// Swapped QK^T via mfma_32x32x16 (A=K, B=Q): lane owns q = l&31; S-regs map
// k_local = (r&3)+8(r>>2)+4h (h=l>>5).  ALiBi bias + static margin folded
// into acc init (k-slot part) + one scalar fkv per tile (kv0 part).
// P stays in registers: cvt_pk pairs feed PV's A-frag directly under the
// permuted-kappa k-slot assignment; V's global layout (Vt_perm) absorbs it.
// K/V LDS: [64 rows][64 cols], granule XOR-swizzle ^(row&7), staged via
// pre-swizzled global source (both-sides rule).
__global__ __launch_bounds__(256, 3) void flash_alibi(
    const unsigned short* __restrict__ Q, const unsigned short* __restrict__ Kb,
    const unsigned short* __restrict__ Vt, unsigned short* __restrict__ O0,
    unsigned short* __restrict__ O1, float* __restrict__ L0,
    float* __restrict__ L1) {
  __shared__ alignas(16) unsigned short Kl[2 * 4096];
  __shared__ alignas(16) unsigned short Vl[2 * 4096];
  const int t = threadIdx.x, w = t >> 6, l = t & 63;
  const int l31 = l & 31, h = l >> 5, lsw = l31 & 7;
  const int g = blockIdx.x;
  const int qt = 15 - (g >> 6);
  const int z = (g & 63) >> 1, s = g & 1;
  const int q0 = qt * 128, hd = z & 15;
  const float slope2 = exp2f(-0.5f * (float)(hd + 1)) * 1.4426950408889634f;
  const int qrow = q0 + w * 32;
  const int qi = qrow + l31;  // this lane's q row

  short8 qf[4];
#pragma unroll
  for (int ks = 0; ks < 4; ks++)
    qf[ks] = *(const short8*)&Q[(z * 2048 + qi) * 64 + ks * 16 + h * 8];

  // acc init: slope2*(k_slot - q) - 10  (k_slot = kc[r]+4h; kv0 added later)
  f32x16 binit;
#pragma unroll
  for (int r = 0; r < 16; r++)
    binit[r] =
        fmaf(slope2, (float)((r & 3) + 8 * (r >> 2) + 4 * h - qi), -10.0f);

  f32x16 accO[2];
  float lsum = 0.f;
#pragma unroll
  for (int nd = 0; nd < 2; nd++)
#pragma unroll
    for (int r = 0; r < 16; r++) accO[nd][r] = 0.f;

  const int sr = t >> 3, sgr = t & 7;
  const int it0 = s ? (qt + 1) : 0;
  const int nt = qt + 1;

#define ISSUE_LOADS(KV0, BUF)                                                 \
  {                                                                           \
    unsigned short* Kd = &Kl[(BUF) * 4096];                                   \
    unsigned short* Vd = &Vl[(BUF) * 4096];                                   \
    const int sx = (sgr ^ (sr & 7)) * 8;                                      \
    gl2lds16(&Kb[(z * 2048 + (KV0) + sr) * 64 + sx], &Kd[t * 8]);             \
    gl2lds16(&Kb[(z * 2048 + (KV0) + 32 + sr) * 64 + sx],                     \
             &Kd[2048 + t * 8]);                                              \
    gl2lds16(&Vt[(z * 64 + sr) * 2048 + (KV0) + sx], &Vd[t * 8]);             \
    gl2lds16(&Vt[(z * 64 + 32 + sr) * 2048 + (KV0) + sx],                     \
             &Vd[2048 + t * 8]);                                              \
  }

  ISSUE_LOADS(it0 * 64, 0)

  for (int ii = 0; ii < nt; ++ii) {
    __syncthreads();  // buf (ii&1) ready
    const int kv0 = (it0 + ii) * 64;
    if (ii + 1 < nt) ISSUE_LOADS(kv0 + 64, (ii + 1) & 1)
    if (kv0 > qrow + 31) continue;  // fully masked for this wave
    const unsigned short* Kc = &Kl[(ii & 1) * 4096];
    const unsigned short* Vc = &Vl[(ii & 1) * 4096];

    // QK^T (swapped): accS[ni] over kv rows ni*32..+31
    f32x16 accS[2];
    accS[0] = binit;
    accS[1] = binit;
#pragma unroll
    for (int ks = 0; ks < 4; ks++) {
      short8 kf0 =
          *(const short8*)&Kc[l31 * 64 + (((ks * 2 + h) ^ lsw) * 8)];
      short8 kf1 =
          *(const short8*)&Kc[(32 + l31) * 64 + (((ks * 2 + h) ^ lsw) * 8)];
      accS[0] = __builtin_amdgcn_mfma_f32_32x32x16_bf16(kf0, qf[ks], accS[0],
                                                        0, 0, 0);
      accS[1] = __builtin_amdgcn_mfma_f32_32x32x16_bf16(kf1, qf[ks], accS[1],
                                                        0, 0, 0);
    }

    const bool needMask = (kv0 + 63 > qrow);  // diagonal tile (either side)
#pragma unroll
    for (int ni = 0; ni < 2; ni++) {
      const float fkv = (float)(kv0 + 32 * ni);
      float ps[16];
#pragma unroll
      for (int r = 0; r < 16; r++)
        ps[r] = __builtin_amdgcn_exp2f(fmaf(slope2, fkv, accS[ni][r]));
      if (needMask) {
        const int kb = kv0 + 32 * ni + 4 * h;
#pragma unroll
        for (int r = 0; r < 16; r++)
          if (kb + ((r & 3) + 8 * (r >> 2)) > qi) ps[r] = 0.f;
      }
      lsum += (((ps[0] + ps[1]) + (ps[2] + ps[3])) +
               ((ps[4] + ps[5]) + (ps[6] + ps[7]))) +
              (((ps[8] + ps[9]) + (ps[10] + ps[11])) +
               ((ps[12] + ps[13]) + (ps[14] + ps[15])));
      unsigned pk[8];
#pragma unroll
      for (int i = 0; i < 8; i++) pk[i] = cvtpk_bf(ps[2 * i], ps[2 * i + 1]);
      // PV for this ni: A-frag = own pk words (permuted-kappa), B = Vt_perm.
#pragma unroll
      for (int kp = 0; kp < 2; kp++) {
        uint4v pw = {pk[kp * 4 + 0], pk[kp * 4 + 1], pk[kp * 4 + 2],
                     pk[kp * 4 + 3]};
        short8 pa = __builtin_bit_cast(short8, pw);
#pragma unroll
        for (int nd = 0; nd < 2; nd++) {
          short8 vf = *(const short8*)&Vc[(nd * 32 + l31) * 64 +
                                          ((((ni * 2 + kp) * 2 + h) ^ lsw) * 8)];
          accO[nd] = __builtin_amdgcn_mfma_f32_32x32x16_bf16(pa, vf, accO[nd],
                                                             0, 0, 0);
        }
      }
    }
  }
#undef ISSUE_LOADS

  // epilogue: write PARTIAL O (no normalization) + partial l
  unsigned short* Op = s ? O1 : O0;
  float* Lp = s ? L1 : L0;
  float lv = lsum + __shfl_xor(lsum, 32);
  if (l < 32) Lp[z * 2048 + qrow + l] = lv;
#pragma unroll
  for (int nd = 0; nd < 2; nd++)
#pragma unroll
    for (int r = 0; r < 16; r++) {
      int tg = qrow + (r & 3) + 8 * (r >> 2) + 4 * h;
      Op[(z * 2048 + tg) * 64 + nd * 32 + l31] = f2bf(accO[nd][r]);
    }
}

// ---------------- combine: O=(O0+O1)/(l0+l1), (z,t,d) -> (b,t,h*64+d) ------
__global__ __launch_bounds__(256) void combine(
    const unsigned short* __restrict__ O0, const unsigned short* __restrict__ O1,
    const float* __restrict__ L0, const float* __restrict__ L1,
    unsigned short* __restrict__ Ob) {
  int idx = (blockIdx.x * 256 + threadIdx.x) * 8;  // flat (z,t,d)
  int z = idx >> 17, rem = idx & 131071;
  int tt = rem >> 6, d = rem & 63;
  short8 a = *(const short8*)(O0 + idx);
  short8 b = *(const short8*)(O1 + idx);
  float inv = 1.0f / (L0[z * 2048 + tt] + L1[z * 2048 + tt]);
  short8 o;
#pragma unroll
  for (int j = 0; j < 8; j++) {
    float v = (bf2f((unsigned short)a[j]) + bf2f((unsigned short)b[j])) * inv;
    o[j] = (short)f2bf(v);
  }
  int bq = z >> 4, h = z & 15;
  *(short8*)(Ob + (bq * 2048 + tt) * 1024 + h * 64 + d) = o;
}

// ---------------------------------------------------------------------------
extern "C" void kernel_launch(void* const* d_in, const int* in_sizes, int n_in,
                              void* d_out, int out_size, void* d_ws,
                              size_t ws_size, hipStream_t stream) {
  const float* x = (const float*)d_in[0];
  const float* Wq = (const float*)d_in[1];
  const float* Wk = (const float*)d_in[2];
  const float* Wv = (const float*)d_in[3];
  const float* Wo = (const float*)d_in[4];

  char* p = (char*)d_ws;
  unsigned short* xb = (unsigned short*)p;  p += 4096 * 1024 * 2;  // O0 after qkv
  unsigned short* wqb = (unsigned short*)p; p += 1024 * 1024 * 2;
  unsigned short* wkb = (unsigned short*)p; p += 1024 * 1024 * 2;
  unsigned short* wvb = (unsigned short*)p; p += 1024 * 1024 * 2;
  unsigned short* wob = (unsigned short*)p; p += 1024 * 1024 * 2;
  unsigned short* Qb = (unsigned short*)p;  p += 32 * 2048 * 64 * 2;  // Ob after flash
  unsigned short* Kbf = (unsigned short*)p; p += 32 * 2048 * 64 * 2;
  unsigned short* Vtb = (unsigned short*)p; p += 32 * 2048 * 64 * 2;
  unsigned short* O1 = (unsigned short*)p;  p += 32 * 2048 * 64 * 2;
  float* L0 = (float*)p;                    p += 32 * 2048 * 4;
  float* L1 = (float*)p;                    p += 32 * 2048 * 4;
  unsigned short* O0 = xb;  // xb dead after gemm_qkv
  unsigned short* Ob = Qb;  // Qb dead after flash

  cvt_all<<<8192, 256, 0, stream>>>(x, Wq, Wk, Wv, Wo, xb, wqb, wkb, wvb, wob);
  gemm_qkv<<<dim3(12, 16), 512, 0, stream>>>(xb, wqb, wkb, wvb, Qb, Kbf, Vtb);
  flash_alibi<<<1024, 256, 0, stream>>>(Qb, Kbf, Vtb, O0, O1, L0, L1);
  combine<<<2048, 256, 0, stream>>>(O0, O1, L0, L1, Ob);
  gemm_o<<<512, 256, 0, stream>>>(Ob, wob, (float*)d_out);
}